// Round 6
// baseline (186.303 us; speedup 1.0000x reference)
//
#include <hip/hip_runtime.h>
#include <hip/hip_bf16.h>

#define TAU_INV_LOG2E 14.4269504088896340736f  // (1/0.1) * log2(e)
#define EPS 1e-8f

typedef __attribute__((ext_vector_type(8))) short bf16x8;
typedef __attribute__((ext_vector_type(4))) float f32x4;

static __device__ __forceinline__ unsigned short f2bf(float f) {
    unsigned int u = __float_as_uint(f);
    unsigned int r = (u + 0x7fffu + ((u >> 16) & 1u)) >> 16;
    return (unsigned short)r;
}

static __device__ __forceinline__ void glds16(const void* g, void* l) {
    __builtin_amdgcn_global_load_lds(
        (const __attribute__((address_space(1))) unsigned int*)g,
        (__attribute__((address_space(3))) unsigned int*)l,
        16, 0, 0);
}

// Kernel 1: L2-normalize rows of x (N x 256 fp32) -> xn (bf16); zero rowsum
// and the done-ticket counter.
__global__ __launch_bounds__(256) void normalize_kernel(
    const float* __restrict__ x, unsigned short* __restrict__ xn,
    float* __restrict__ rowsum, int* __restrict__ done, int N) {
    const int wave = threadIdx.x >> 6;
    const int lane = threadIdx.x & 63;
    const int row  = blockIdx.x * 4 + wave;
    if (row >= N) return;

    if (threadIdx.x < 4) {
        int rr = blockIdx.x * 4 + threadIdx.x;
        if (rr < N) rowsum[rr] = 0.0f;
    }
    if (blockIdx.x == 0 && threadIdx.x == 0) *done = 0;

    const float4 v = ((const float4*)(x + (size_t)row * 256))[lane];
    float s = v.x * v.x + v.y * v.y + v.z * v.z + v.w * v.w;
    s += __shfl_xor(s, 1);
    s += __shfl_xor(s, 2);
    s += __shfl_xor(s, 4);
    s += __shfl_xor(s, 8);
    s += __shfl_xor(s, 16);
    s += __shfl_xor(s, 32);
    const float norm = fmaxf(sqrtf(s), 1e-12f);
    const float rinv = 1.0f / norm;

    ushort4 o;
    o.x = f2bf(v.x * rinv);
    o.y = f2bf(v.y * rinv);
    o.z = f2bf(v.z * rinv);
    o.w = f2bf(v.w * rinv);
    ((ushort4*)(xn + (size_t)row * 256))[lane] = o;
}

// Kernel 2: symmetric fused S = Xn*Xn^T, 128x256 block tile (two 128x128
// tiles, domino cover of the upper triangle). 256 threads = 4 waves; wave w
// covers its 64-col slab over all 128 rows (acc 8x4 f32x4 = 128 AGPR).
// DMA staging (global_load_lds x16B, XOR swizzle, 0 conflicts), BK=64.
// exp(S/tau), diag zeroed, row sums + symmetric col sums via atomics.
// Last-arriving block computes the final loss (saves a launch).
__global__ __launch_bounds__(256, 2) void gemm_exp_rowsum_kernel(
    const unsigned short* __restrict__ xn, float* __restrict__ rowsum,
    int* __restrict__ done, float* __restrict__ out, int N, int nblocks) {
    const int D = 256;
    __shared__ unsigned short As[16 * 512];  // 128 rows x 64 cols = 16 KB
    __shared__ unsigned short Bs[32 * 512];  // 256 rows x 64 cols = 32 KB
    __shared__ int ticket_s;
    __shared__ float red[4];

    const int tid   = threadIdx.x;
    const int wave  = tid >> 6;
    const int lane  = tid & 63;
    const int quad  = lane >> 4;
    const int l16   = lane & 15;

    // integer decode: block -> (bi, jp); row-tile bi (128 rows), col-pair jp
    // (256 cols at jp*256). jp >= bi/2 guarantees right tile is upper-tri.
    int bi = 0, trem = blockIdx.x;
    while (trem >= 32 - (bi >> 1)) { trem -= 32 - (bi >> 1); ++bi; }
    const int jp = (bi >> 1) + trem;

    const int iBase = bi * 128;
    const int jBase = jp * 256;

    const int myTile = wave >> 1;            // 0 = left 128 cols, 1 = right
    const int bj     = 2 * jp + myTile;
    const bool valid = (bj >= bi);           // left tile of odd-bi rows is waste
    const bool colOk = (bj > bi);            // strict upper: add col sums

    const int lrow = lane >> 3;              // row within 8-row DMA chunk
    const int lsw  = (lane & 7) ^ lrow;      // swizzled 16B col-chunk

    f32x4 acc[8][4];
    #pragma unroll
    for (int mt = 0; mt < 8; ++mt)
        #pragma unroll
        for (int nt = 0; nt < 4; ++nt)
            acc[mt][nt] = (f32x4){0.f, 0.f, 0.f, 0.f};

    for (int k0 = 0; k0 < D; k0 += 64) {
        // 48 chunk-DMAs (16 A + 32 B), 12 per wave; each glds16 moves one
        // 8-row x 64-col chunk (1 KB) with the verified XOR swizzle.
        #pragma unroll
        for (int it = 0; it < 12; ++it) {
            const int ch = wave * 12 + it;
            if (ch < 16) {
                glds16(xn + (size_t)(iBase + ch * 8 + lrow) * D + k0 + lsw * 8,
                       As + ch * 512);
            } else {
                const int q = ch - 16;
                glds16(xn + (size_t)(jBase + q * 8 + lrow) * D + k0 + lsw * 8,
                       Bs + q * 512);
            }
        }
        __syncthreads();

        if (valid) {
            #pragma unroll
            for (int kh = 0; kh < 2; ++kh) {
                const int cA = kh * 4 + quad;
                bf16x8 a[8], b[4];
                #pragma unroll
                for (int mt = 0; mt < 8; ++mt) {
                    const int rA = mt * 16 + l16;
                    a[mt] = *(const bf16x8*)(As + (rA >> 3) * 512 +
                                             (rA & 7) * 64 + ((cA ^ (rA & 7)) * 8));
                }
                #pragma unroll
                for (int nt = 0; nt < 4; ++nt) {
                    const int rB = myTile * 128 + (wave & 1) * 64 + nt * 16 + l16;
                    b[nt] = *(const bf16x8*)(Bs + (rB >> 3) * 512 +
                                             (rB & 7) * 64 + ((cA ^ (rB & 7)) * 8));
                }
                #pragma unroll
                for (int mt = 0; mt < 8; ++mt)
                    #pragma unroll
                    for (int nt = 0; nt < 4; ++nt)
                        acc[mt][nt] = __builtin_amdgcn_mfma_f32_16x16x32_bf16(
                            a[mt], b[nt], acc[mt][nt], 0, 0, 0);
            }
        }
        __syncthreads();
    }

    // Epilogue. C/D layout: col = l16, row = quad*4 + reg  [m89/m91]
    if (valid) {
        const int colBase = jBase + myTile * 128 + (wave & 1) * 64;
        float csum[4] = {0.f, 0.f, 0.f, 0.f};
        #pragma unroll
        for (int mt = 0; mt < 8; ++mt) {
            const int gi0 = iBase + mt * 16 + quad * 4;
            float rs[4] = {0.f, 0.f, 0.f, 0.f};
            #pragma unroll
            for (int nt = 0; nt < 4; ++nt) {
                const int gj = colBase + nt * 16 + l16;
                #pragma unroll
                for (int r = 0; r < 4; ++r) {
                    float e = __builtin_amdgcn_exp2f(acc[mt][nt][r] * TAU_INV_LOG2E);
                    if (gi0 + r == gj) e = 0.0f;  // diagonal (diag tiles only)
                    rs[r] += e;
                    csum[nt] += e;
                }
            }
            #pragma unroll
            for (int r = 0; r < 4; ++r) {
                float s = rs[r];
                s += __shfl_xor(s, 1);
                s += __shfl_xor(s, 2);
                s += __shfl_xor(s, 4);
                s += __shfl_xor(s, 8);
                if (l16 == 0) atomicAdd(&rowsum[gi0 + r], s);
            }
        }
        if (colOk) {
            #pragma unroll
            for (int nt = 0; nt < 4; ++nt) {
                float s = csum[nt];
                s += __shfl_xor(s, 16);
                s += __shfl_xor(s, 32);
                if (quad == 0) atomicAdd(&rowsum[colBase + nt * 16 + l16], s);
            }
        }
    }

    // Last block computes the loss.
    __threadfence();
    if (tid == 0)
        ticket_s = __hip_atomic_fetch_add(done, 1, __ATOMIC_ACQ_REL,
                                          __HIP_MEMORY_SCOPE_AGENT);
    __syncthreads();
    if (ticket_s == nblocks - 1) {
        const float inv = 1.0f / (float)(N - 1);
        float accv = 0.f;
        for (int i = tid; i < N; i += 256) {
            float v = __hip_atomic_load(&rowsum[i], __ATOMIC_RELAXED,
                                        __HIP_MEMORY_SCOPE_AGENT);
            accv += logf(v * inv + EPS);
        }
        accv += __shfl_xor(accv, 1);
        accv += __shfl_xor(accv, 2);
        accv += __shfl_xor(accv, 4);
        accv += __shfl_xor(accv, 8);
        accv += __shfl_xor(accv, 16);
        accv += __shfl_xor(accv, 32);
        if (lane == 0) red[wave] = accv;
        __syncthreads();
        if (tid == 0)
            out[0] = (red[0] + red[1] + red[2] + red[3]) / (float)N;
    }
}

extern "C" void kernel_launch(void* const* d_in, const int* in_sizes, int n_in,
                              void* d_out, int out_size, void* d_ws, size_t ws_size,
                              hipStream_t stream) {
    const float* x = (const float*)d_in[0];
    const int D = 256;
    const int N = in_sizes[0] / D;  // 8192

    unsigned short* xn = (unsigned short*)d_ws;  // N*D bf16 = 4 MB
    float* rowsum = (float*)((char*)d_ws + (size_t)N * D * sizeof(unsigned short));
    int* done = (int*)((char*)d_ws + (size_t)N * D * sizeof(unsigned short) +
                       (size_t)N * sizeof(float));
    float* out = (float*)d_out;

    normalize_kernel<<<(N + 3) / 4, 256, 0, stream>>>(x, xn, rowsum, done, N);

    // domino cover of upper triangle: sum_{bi=0}^{63} (32 - bi/2) = 1056
    const int nblocks = 1056;
    gemm_exp_rowsum_kernel<<<nblocks, 256, 0, stream>>>(xn, rowsum, done, out,
                                                        N, nblocks);
}

// Round 7
// 146.879 us; speedup vs baseline: 1.2684x; 1.2684x over previous
//
#include <hip/hip_runtime.h>
#include <hip/hip_bf16.h>

#define TAU_INV_LOG2E 14.4269504088896340736f  // (1/0.1) * log2(e)
#define EPS 1e-8f

typedef __attribute__((ext_vector_type(8))) short bf16x8;
typedef __attribute__((ext_vector_type(4))) float f32x4;

static __device__ __forceinline__ unsigned short f2bf(float f) {
    unsigned int u = __float_as_uint(f);
    unsigned int r = (u + 0x7fffu + ((u >> 16) & 1u)) >> 16;
    return (unsigned short)r;
}

static __device__ __forceinline__ void glds16(const void* g, void* l) {
    __builtin_amdgcn_global_load_lds(
        (const __attribute__((address_space(1))) unsigned int*)g,
        (__attribute__((address_space(3))) unsigned int*)l,
        16, 0, 0);
}

// Kernel 1: L2-normalize rows of x (N x 256 fp32) -> xn (bf16); zero rowsum
// and the done-ticket.
__global__ __launch_bounds__(256) void normalize_kernel(
    const float* __restrict__ x, unsigned short* __restrict__ xn,
    float* __restrict__ rowsum, int* __restrict__ done, int N) {
    const int wave = threadIdx.x >> 6;
    const int lane = threadIdx.x & 63;
    const int row  = blockIdx.x * 4 + wave;
    if (row >= N) return;

    if (threadIdx.x < 4) {
        int rr = blockIdx.x * 4 + threadIdx.x;
        if (rr < N) rowsum[rr] = 0.0f;
    }
    if (blockIdx.x == 0 && threadIdx.x == 0) *done = 0;

    const float4 v = ((const float4*)(x + (size_t)row * 256))[lane];
    float s = v.x * v.x + v.y * v.y + v.z * v.z + v.w * v.w;
    s += __shfl_xor(s, 1);
    s += __shfl_xor(s, 2);
    s += __shfl_xor(s, 4);
    s += __shfl_xor(s, 8);
    s += __shfl_xor(s, 16);
    s += __shfl_xor(s, 32);
    const float norm = fmaxf(sqrtf(s), 1e-12f);
    const float rinv = 1.0f / norm;

    ushort4 o;
    o.x = f2bf(v.x * rinv);
    o.y = f2bf(v.y * rinv);
    o.z = f2bf(v.z * rinv);
    o.w = f2bf(v.w * rinv);
    ((ushort4*)(xn + (size_t)row * 256))[lane] = o;
}

// decode upper-triangle tile index t -> (bi, bj), bi <= bj, B tiles per dim
static __device__ __forceinline__ void decode_tile(int t, int B, int& bi, int& bj) {
    int x = 0, rem = t;
    while (rem >= B - x) { rem -= B - x; ++x; }
    bi = x;
    bj = x + rem;
}

// Kernel 2: persistent-block symmetric fused S = Xn*Xn^T, 128x128 tiles
// (upper triangle, 2080 tiles over 512 blocks, ~4 tiles each).
// Double-buffered LDS (A+B, 2x32KB), ONE barrier per K-round; next-tile
// round-0 DMA is issued before the epilogue so its latency hides under
// ~800 cyc of AGPR/exp/shfl/atomic work. Last block computes the loss.
__global__ __launch_bounds__(256, 2) void gemm_exp_rowsum_kernel(
    const unsigned short* __restrict__ xn, float* __restrict__ rowsum,
    int* __restrict__ done, float* __restrict__ out, int N, int nblocks) {
    const int D = 256;
    __shared__ unsigned short As[2][16 * 512];  // 2 x 16 KB
    __shared__ unsigned short Bs[2][16 * 512];  // 2 x 16 KB
    __shared__ int ticket_s;
    __shared__ float red[4];

    const int tid   = threadIdx.x;
    const int wave  = tid >> 6;
    const int lane  = tid & 63;
    const int waveM = wave >> 1;
    const int waveN = wave & 1;
    const int quad  = lane >> 4;
    const int l16   = lane & 15;

    const int lrow = lane >> 3;            // row within 8-row DMA chunk
    const int lsw  = (lane & 7) ^ lrow;    // swizzled 16B col-chunk (0 conflicts)

    const int B = N >> 7;                  // 64
    const int T = B * (B + 1) / 2;         // 2080
    const int G = gridDim.x;

    int t = blockIdx.x;
    int bi, bj;
    decode_tile(t, B, bi, bj);
    bool diag  = (bi == bj);
    int iBase  = bi * 128;
    int jBase  = bj * 128;

    // prologue: stage tile-0 round-0 into buffer 0
    #pragma unroll
    for (int it = 0; it < 4; ++it) {
        const int q = wave * 4 + it;
        const int row = q * 8 + lrow;
        glds16(xn + (size_t)(iBase + row) * D + lsw * 8, &As[0][q * 512]);
        if (!diag)
            glds16(xn + (size_t)(jBase + row) * D + lsw * 8, &Bs[0][q * 512]);
    }
    int pbuf = 0;

    while (true) {
        f32x4 acc[4][4];
        #pragma unroll
        for (int mt = 0; mt < 4; ++mt)
            #pragma unroll
            for (int nt = 0; nt < 4; ++nt)
                acc[mt][nt] = (f32x4){0.f, 0.f, 0.f, 0.f};

        // pre-decode next tile (uniform scalar, overlaps with everything)
        const int tn = t + G;
        const bool haveN = (tn < T);
        int biN = 0, bjN = 0;
        if (haveN) decode_tile(tn, B, biN, bjN);
        const bool diagN = (biN == bjN);
        const int iBaseN = biN * 128, jBaseN = bjN * 128;

        #pragma unroll
        for (int r = 0; r < 4; ++r) {
            __syncthreads();  // drains the DMA filling buffer pbuf (issued one
                              // full compute round ago) + guards ~pbuf overwrite
            // issue next DMA into the other buffer
            if (r < 3) {
                #pragma unroll
                for (int it = 0; it < 4; ++it) {
                    const int q = wave * 4 + it;
                    const int row = q * 8 + lrow;
                    glds16(xn + (size_t)(iBase + row) * D + (r + 1) * 64 + lsw * 8,
                           &As[pbuf ^ 1][q * 512]);
                    if (!diag)
                        glds16(xn + (size_t)(jBase + row) * D + (r + 1) * 64 + lsw * 8,
                               &Bs[pbuf ^ 1][q * 512]);
                }
            } else if (haveN) {
                #pragma unroll
                for (int it = 0; it < 4; ++it) {
                    const int q = wave * 4 + it;
                    const int row = q * 8 + lrow;
                    glds16(xn + (size_t)(iBaseN + row) * D + lsw * 8,
                           &As[pbuf ^ 1][q * 512]);
                    if (!diagN)
                        glds16(xn + (size_t)(jBaseN + row) * D + lsw * 8,
                               &Bs[pbuf ^ 1][q * 512]);
                }
            }

            // compute round r from buffer pbuf
            const unsigned short* Ab = &As[pbuf][0];
            const unsigned short* Bb = diag ? &As[pbuf][0] : &Bs[pbuf][0];
            #pragma unroll
            for (int kh = 0; kh < 2; ++kh) {
                const int cA = kh * 4 + quad;
                bf16x8 a[4], b[4];
                #pragma unroll
                for (int tt = 0; tt < 4; ++tt) {
                    const int rA = waveM * 64 + tt * 16 + l16;
                    a[tt] = *(const bf16x8*)(Ab + (rA >> 3) * 512 +
                                             (rA & 7) * 64 + ((cA ^ (rA & 7)) * 8));
                    const int rB = waveN * 64 + tt * 16 + l16;
                    b[tt] = *(const bf16x8*)(Bb + (rB >> 3) * 512 +
                                             (rB & 7) * 64 + ((cA ^ (rB & 7)) * 8));
                }
                #pragma unroll
                for (int mt = 0; mt < 4; ++mt)
                    #pragma unroll
                    for (int nt = 0; nt < 4; ++nt)
                        acc[mt][nt] = __builtin_amdgcn_mfma_f32_16x16x32_bf16(
                            a[mt], b[nt], acc[mt][nt], 0, 0, 0);
            }
            pbuf ^= 1;
        }

        // Epilogue (AGPR/exp/shfl/atomics only — overlaps next-tile DMA).
        // C/D layout: col = l16, row = quad*4 + reg  [m89/m91]
        {
            float csum[4] = {0.f, 0.f, 0.f, 0.f};
            #pragma unroll
            for (int mt = 0; mt < 4; ++mt) {
                const int gi0 = iBase + waveM * 64 + mt * 16 + quad * 4;
                float rs[4] = {0.f, 0.f, 0.f, 0.f};
                #pragma unroll
                for (int nt = 0; nt < 4; ++nt) {
                    const int gj = jBase + waveN * 64 + nt * 16 + l16;
                    #pragma unroll
                    for (int r = 0; r < 4; ++r) {
                        float e = __builtin_amdgcn_exp2f(acc[mt][nt][r] * TAU_INV_LOG2E);
                        if (gi0 + r == gj) e = 0.0f;  // diagonal (diag tiles)
                        rs[r] += e;
                        csum[nt] += e;
                    }
                }
                #pragma unroll
                for (int r = 0; r < 4; ++r) {
                    float s = rs[r];
                    s += __shfl_xor(s, 1);
                    s += __shfl_xor(s, 2);
                    s += __shfl_xor(s, 4);
                    s += __shfl_xor(s, 8);
                    if (l16 == 0) atomicAdd(&rowsum[gi0 + r], s);
                }
            }
            if (!diag) {  // strict upper tiles mirror into col sums
                #pragma unroll
                for (int nt = 0; nt < 4; ++nt) {
                    float s = csum[nt];
                    s += __shfl_xor(s, 16);
                    s += __shfl_xor(s, 32);
                    if (quad == 0)
                        atomicAdd(&rowsum[jBase + waveN * 64 + nt * 16 + l16], s);
                }
            }
        }

        if (!haveN) break;
        t = tn; bi = biN; bj = bjN; diag = diagN; iBase = iBaseN; jBase = jBaseN;
    }

    // Last-arriving block computes the loss.
    __threadfence();
    if (tid == 0)
        ticket_s = __hip_atomic_fetch_add(done, 1, __ATOMIC_ACQ_REL,
                                          __HIP_MEMORY_SCOPE_AGENT);
    __syncthreads();
    if (ticket_s == nblocks - 1) {
        const float inv = 1.0f / (float)(N - 1);
        float accv = 0.f;
        for (int i = tid; i < N; i += 256) {
            float v = __hip_atomic_load(&rowsum[i], __ATOMIC_RELAXED,
                                        __HIP_MEMORY_SCOPE_AGENT);
            accv += logf(v * inv + EPS);
        }
        accv += __shfl_xor(accv, 1);
        accv += __shfl_xor(accv, 2);
        accv += __shfl_xor(accv, 4);
        accv += __shfl_xor(accv, 8);
        accv += __shfl_xor(accv, 16);
        accv += __shfl_xor(accv, 32);
        if (lane == 0) red[wave] = accv;
        __syncthreads();
        if (tid == 0)
            out[0] = (red[0] + red[1] + red[2] + red[3]) / (float)N;
    }
}

extern "C" void kernel_launch(void* const* d_in, const int* in_sizes, int n_in,
                              void* d_out, int out_size, void* d_ws, size_t ws_size,
                              hipStream_t stream) {
    const float* x = (const float*)d_in[0];
    const int D = 256;
    const int N = in_sizes[0] / D;  // 8192

    unsigned short* xn = (unsigned short*)d_ws;  // N*D bf16 = 4 MB
    float* rowsum = (float*)((char*)d_ws + (size_t)N * D * sizeof(unsigned short));
    int* done = (int*)((char*)d_ws + (size_t)N * D * sizeof(unsigned short) +
                       (size_t)N * sizeof(float));
    float* out = (float*)d_out;

    normalize_kernel<<<(N + 3) / 4, 256, 0, stream>>>(x, xn, rowsum, done, N);

    const int nblocks = 512;  // persistent, ~4 tiles each (T = 2080)
    gemm_exp_rowsum_kernel<<<nblocks, 256, 0, stream>>>(xn, rowsum, done, out,
                                                        N, nblocks);
}